// Round 1
// baseline (2399.996 us; speedup 1.0000x reference)
//
#include <hip/hip_runtime.h>
#include <hip/hip_bf16.h>
#include <math.h>

#define S_LEN 4096
#define DHEAD 128
#define NHEAD 8
#define LASTQ 64
#define V_TOPK 1024
#define S_TOPK 2048
#define FORCE_V 30
#define FORCE_S 100

// 1/sqrt(128) (matches float32(np.sqrt(128)) to well below output tolerance)
#define SCALE 0.08838834764831845f

// ---------------------------------------------------------------------------
// Phase A: for each (head h, last-query qi): causal softmax row over all keys,
// atomically accumulate probs into vertical[j] and slash[qpos - j].
// ---------------------------------------------------------------------------
__global__ __launch_bounds__(256) void pattern_rows(const float* __restrict__ q,
                                                    const float* __restrict__ k,
                                                    float* __restrict__ vertical,
                                                    float* __restrict__ slash) {
    int h  = blockIdx.x >> 6;   // /64
    int qi = blockIdx.x & 63;
    int qpos = S_LEN - LASTQ + qi;
    int t = threadIdx.x;

    __shared__ float qrow[DHEAD];
    __shared__ float sc[S_LEN];
    __shared__ float red[256];

    const float* qp = q + ((size_t)h * S_LEN + qpos) * DHEAD;
    if (t < DHEAD) qrow[t] = qp[t];
    __syncthreads();

    const float* kh = k + (size_t)h * S_LEN * DHEAD;

    float lmax = -__builtin_inff();
    for (int j = t; j < S_LEN; j += 256) {
        const float* kp = kh + (size_t)j * DHEAD;
        float dot = 0.f;
#pragma unroll 8
        for (int d = 0; d < DHEAD; d += 4) {
            float4 kv = *(const float4*)(kp + d);
            dot += qrow[d] * kv.x + qrow[d + 1] * kv.y + qrow[d + 2] * kv.z + qrow[d + 3] * kv.w;
        }
        float s = (j <= qpos) ? dot * SCALE : -__builtin_inff();
        sc[j] = s;
        lmax = fmaxf(lmax, s);
    }
    red[t] = lmax;
    __syncthreads();
    for (int off = 128; off > 0; off >>= 1) {
        if (t < off) red[t] = fmaxf(red[t], red[t + off]);
        __syncthreads();
    }
    float m = red[0];
    __syncthreads();   // everyone has read red[0] before it is reused

    float lsum = 0.f;
    for (int j = t; j < S_LEN; j += 256) {
        float s = sc[j];
        float p = (s == -__builtin_inff()) ? 0.f : expf(s - m);
        sc[j] = p;
        lsum += p;
    }
    red[t] = lsum;
    __syncthreads();
    for (int off = 128; off > 0; off >>= 1) {
        if (t < off) red[t] += red[t + off];
        __syncthreads();
    }
    float inv = 1.0f / red[0];

    for (int j = t; j <= qpos; j += 256) {
        float p = sc[j] * inv;
        atomicAdd(&vertical[h * S_LEN + j], p);
        atomicAdd(&slash[h * S_LEN + (qpos - j)], p);
    }
}

// ---------------------------------------------------------------------------
// Phase B: per (head, {vertical,slash}) exact k-th-largest via radix select,
// then write membership bitmask (key >= T). Forced-prefix entries become +inf.
// ---------------------------------------------------------------------------
__global__ __launch_bounds__(256) void topk_mask(const float* __restrict__ vertical,
                                                 const float* __restrict__ slash,
                                                 unsigned* __restrict__ col_mask,
                                                 unsigned* __restrict__ diag_mask) {
    int h   = blockIdx.x >> 1;
    int sel = blockIdx.x & 1;
    const float* src = sel ? (slash + h * S_LEN) : (vertical + h * S_LEN);
    unsigned* dst    = sel ? (diag_mask + h * (S_LEN / 32)) : (col_mask + h * (S_LEN / 32));
    int kwant  = sel ? S_TOPK : V_TOPK;
    int forced = sel ? FORCE_S : FORCE_V;
    int t = threadIdx.x;

    __shared__ unsigned keys[S_LEN];
    __shared__ int hist[256];
    __shared__ int sh_digit, sh_want;

    for (int j = t; j < S_LEN; j += 256) {
        float f = (j < forced) ? __builtin_inff() : src[j];
        unsigned u = __float_as_uint(f);
        u = (u & 0x80000000u) ? ~u : (u | 0x80000000u);  // monotone map
        keys[j] = u;
    }
    __syncthreads();

    unsigned prefix = 0;
    int want = kwant;
    for (int shift = 24; shift >= 0; shift -= 8) {
        hist[t] = 0;
        __syncthreads();
        for (int j = t; j < S_LEN; j += 256) {
            unsigned key = keys[j];
            bool match = (shift == 24) || (((key ^ prefix) >> (shift + 8)) == 0);
            if (match) atomicAdd(&hist[(key >> shift) & 255u], 1);
        }
        __syncthreads();
        if (t == 0) {
            int cum = 0, d = 255;
            for (; d >= 0; --d) {
                cum += hist[d];
                if (cum >= want) break;
            }
            sh_digit = d;
            sh_want  = want - (cum - hist[d]);
        }
        __syncthreads();
        prefix |= ((unsigned)sh_digit) << shift;
        want = sh_want;
        __syncthreads();
    }
    // prefix == k-th largest key
    for (int w = t; w < S_LEN / 32; w += 256) {
        unsigned bits = 0;
        for (int b = 0; b < 32; ++b)
            if (keys[w * 32 + b] >= prefix) bits |= (1u << b);
        dst[w] = bits;
    }
}

// ---------------------------------------------------------------------------
// Phase C: masked (vertical|slash, causal) flash attention, fp32 vector math.
// Block = 32 q-rows x 256 threads; K/V tiles of 32 in LDS; online softmax.
// ---------------------------------------------------------------------------
#define BR 32
#define BC 32

__global__ __launch_bounds__(256) void sparse_attn(const float* __restrict__ q,
                                                   const float* __restrict__ k,
                                                   const float* __restrict__ v,
                                                   const unsigned* __restrict__ col_mask,
                                                   const unsigned* __restrict__ diag_mask,
                                                   float* __restrict__ out) {
    int h  = blockIdx.x >> 7;    // 128 q-tiles per head
    int qt = blockIdx.x & 127;
    int i0 = qt * BR;
    int t  = threadIdx.x;

    __shared__ float Qs[BR][DHEAD + 1];   // stride 129: conflict-free
    __shared__ float Ks[BC][DHEAD + 1];
    __shared__ float Vs[BC][DHEAD];
    __shared__ float Ps[BR][BC + 1];      // stride 33
    __shared__ float m_sh[BR], l_sh[BR], mn_sh[BR], al_sh[BR];
    __shared__ unsigned cmask[S_LEN / 32], dmask[S_LEN / 32];

    const float* qh = q + (size_t)h * S_LEN * DHEAD;
    const float* kh = k + (size_t)h * S_LEN * DHEAD;
    const float* vh = v + (size_t)h * S_LEN * DHEAD;

    for (int w = t; w < S_LEN / 32; w += 256) {
        cmask[w] = col_mask[h * (S_LEN / 32) + w];
        dmask[w] = diag_mask[h * (S_LEN / 32) + w];
    }
    for (int idx = t; idx < BR * DHEAD / 4; idx += 256) {
        int r = idx >> 5, d4 = idx & 31;
        float4 qv = ((const float4*)(qh + (size_t)(i0 + r) * DHEAD))[d4];
        Qs[r][d4 * 4 + 0] = qv.x; Qs[r][d4 * 4 + 1] = qv.y;
        Qs[r][d4 * 4 + 2] = qv.z; Qs[r][d4 * 4 + 3] = qv.w;
    }
    if (t < BR) { m_sh[t] = -__builtin_inff(); l_sh[t] = 0.f; }

    // QK^T mapping: thread -> (ri = t>>4 in 0..15, ci = t&15), 2x2 entries
    int ri = t >> 4, ci = t & 15;
    // PV mapping: thread -> (row = t>>3, g = t&7), owns d = g + 8*dd
    int row = t >> 3, g = t & 7;

    float acc[16];
#pragma unroll
    for (int x = 0; x < 16; ++x) acc[x] = 0.f;

    int ntiles = (i0 + BR - 1) / BC + 1;   // causal: up to and including diag tile
    for (int tile = 0; tile < ntiles; ++tile) {
        int j0 = tile * BC;
        __syncthreads();   // prior tile's reads of Ks/Vs/Ps done
        for (int idx = t; idx < BC * DHEAD / 4; idx += 256) {
            int r = idx >> 5, d4 = idx & 31;
            float4 kv = ((const float4*)(kh + (size_t)(j0 + r) * DHEAD))[d4];
            Ks[r][d4 * 4 + 0] = kv.x; Ks[r][d4 * 4 + 1] = kv.y;
            Ks[r][d4 * 4 + 2] = kv.z; Ks[r][d4 * 4 + 3] = kv.w;
            ((float4*)&Vs[r][0])[d4] = ((const float4*)(vh + (size_t)(j0 + r) * DHEAD))[d4];
        }
        __syncthreads();

        // ---- S = Q K^T (2x2 per thread) ----
        {
            int r0 = 2 * ri, r1 = r0 + 1;
            int c0 = 2 * ci, c1 = c0 + 1;
            float s00 = 0.f, s01 = 0.f, s10 = 0.f, s11 = 0.f;
#pragma unroll 4
            for (int d = 0; d < DHEAD; ++d) {
                float qa = Qs[r0][d], qb = Qs[r1][d];
                float ka = Ks[c0][d], kb = Ks[c1][d];
                s00 += qa * ka; s01 += qa * kb;
                s10 += qb * ka; s11 += qb * kb;
            }
            float sv[2][2] = {{s00, s01}, {s10, s11}};
#pragma unroll
            for (int rr = 0; rr < 2; ++rr) {
#pragma unroll
                for (int cc = 0; cc < 2; ++cc) {
                    int i = i0 + r0 + rr;
                    int j = j0 + c0 + cc;
                    bool ok = (j <= i);
                    if (ok) {
                        bool cb = (cmask[j >> 5] >> (j & 31)) & 1u;
                        int o = i - j;
                        bool db = (dmask[o >> 5] >> (o & 31)) & 1u;
                        ok = cb | db;
                    }
                    Ps[r0 + rr][c0 + cc] = ok ? sv[rr][cc] * SCALE : -__builtin_inff();
                }
            }
        }
        __syncthreads();

        // ---- row stats ----
        if (t < BR) {
            float mx = m_sh[t];
            for (int jj = 0; jj < BC; ++jj) mx = fmaxf(mx, Ps[t][jj]);
            mn_sh[t] = mx;
            al_sh[t] = (m_sh[t] == -__builtin_inff()) ? 0.f : expf(m_sh[t] - mx);
        }
        __syncthreads();

        // ---- scores -> p ----
        for (int idx = t; idx < BR * BC; idx += 256) {
            int r = idx >> 5, jj = idx & 31;
            float s = Ps[r][jj];
            Ps[r][jj] = (s == -__builtin_inff()) ? 0.f : expf(s - mn_sh[r]);
        }
        __syncthreads();

        // ---- l/m update (first 32 threads) ----
        if (t < BR) {
            float su = 0.f;
            for (int jj = 0; jj < BC; ++jj) su += Ps[t][jj];
            l_sh[t] = l_sh[t] * al_sh[t] + su;
            m_sh[t] = mn_sh[t];
        }

        // ---- rescale + PV accumulate ----
        {
            float a = al_sh[row];
#pragma unroll
            for (int dd = 0; dd < 16; ++dd) acc[dd] *= a;
#pragma unroll 4
            for (int jj = 0; jj < BC; ++jj) {
                float p = Ps[row][jj];
#pragma unroll
                for (int dd = 0; dd < 16; ++dd)
                    acc[dd] += p * Vs[jj][g + 8 * dd];
            }
        }
    }
    __syncthreads();

    float invl = 1.0f / l_sh[row];
    float* op = out + ((size_t)h * S_LEN + (i0 + row)) * DHEAD;
#pragma unroll
    for (int dd = 0; dd < 16; ++dd) op[g + 8 * dd] = acc[dd] * invl;
}

// ---------------------------------------------------------------------------
extern "C" void kernel_launch(void* const* d_in, const int* in_sizes, int n_in,
                              void* d_out, int out_size, void* d_ws, size_t ws_size,
                              hipStream_t stream) {
    const float* q = (const float*)d_in[0];
    const float* k = (const float*)d_in[1];
    const float* v = (const float*)d_in[2];
    float* out = (float*)d_out;

    float* vertical   = (float*)d_ws;                       // 8*4096 floats
    float* slash      = vertical + NHEAD * S_LEN;           // 8*4096 floats
    unsigned* col_m   = (unsigned*)(slash + NHEAD * S_LEN); // 8*128 words
    unsigned* diag_m  = col_m + NHEAD * (S_LEN / 32);       // 8*128 words

    hipMemsetAsync(d_ws, 0, (size_t)2 * NHEAD * S_LEN * sizeof(float), stream);

    pattern_rows<<<NHEAD * LASTQ, 256, 0, stream>>>(q, k, vertical, slash);
    topk_mask<<<NHEAD * 2, 256, 0, stream>>>(vertical, slash, col_m, diag_m);
    sparse_attn<<<NHEAD * (S_LEN / BR), 256, 0, stream>>>(q, k, v, col_m, diag_m, out);
}

// Round 2
// 454.364 us; speedup vs baseline: 5.2821x; 5.2821x over previous
//
#include <hip/hip_runtime.h>
#include <hip/hip_bf16.h>
#include <math.h>

#define S_LEN 4096
#define DHEAD 128
#define NHEAD 8
#define LASTQ 64
#define V_TOPK 1024
#define S_TOPK 2048
#define FORCE_V 30
#define FORCE_S 100

#define SCALE 0.08838834764831845f

typedef __attribute__((ext_vector_type(8))) short short8;
typedef __attribute__((ext_vector_type(4))) float floatx4;
typedef unsigned long long u64;

__device__ __forceinline__ unsigned short f2bf(float f) {
    unsigned u = __float_as_uint(f);
    unsigned r = (u + 0x7fffu + ((u >> 16) & 1u)) >> 16;   // RNE
    return (unsigned short)r;
}

// ---------------------------------------------------------------------------
// Phase A: per (head, last-query) causal softmax row; accumulate vertical/slash.
// ---------------------------------------------------------------------------
__global__ __launch_bounds__(256) void pattern_rows(const float* __restrict__ q,
                                                    const float* __restrict__ k,
                                                    float* __restrict__ vertical,
                                                    float* __restrict__ slash) {
    int h  = blockIdx.x >> 6;
    int qi = blockIdx.x & 63;
    int qpos = S_LEN - LASTQ + qi;
    int t = threadIdx.x;

    __shared__ float qrow[DHEAD];
    __shared__ float sc[S_LEN];
    __shared__ float red[256];

    const float* qp = q + ((size_t)h * S_LEN + qpos) * DHEAD;
    if (t < DHEAD) qrow[t] = qp[t];
    __syncthreads();

    const float* kh = k + (size_t)h * S_LEN * DHEAD;

    float lmax = -__builtin_inff();
    for (int j = t; j < S_LEN; j += 256) {
        const float* kp = kh + (size_t)j * DHEAD;
        float dot = 0.f;
#pragma unroll 8
        for (int d = 0; d < DHEAD; d += 4) {
            float4 kv = *(const float4*)(kp + d);
            dot += qrow[d] * kv.x + qrow[d + 1] * kv.y + qrow[d + 2] * kv.z + qrow[d + 3] * kv.w;
        }
        float s = (j <= qpos) ? dot * SCALE : -__builtin_inff();
        sc[j] = s;
        lmax = fmaxf(lmax, s);
    }
    red[t] = lmax;
    __syncthreads();
    for (int off = 128; off > 0; off >>= 1) {
        if (t < off) red[t] = fmaxf(red[t], red[t + off]);
        __syncthreads();
    }
    float m = red[0];
    __syncthreads();

    float lsum = 0.f;
    for (int j = t; j < S_LEN; j += 256) {
        float s = sc[j];
        float p = (s == -__builtin_inff()) ? 0.f : expf(s - m);
        sc[j] = p;
        lsum += p;
    }
    red[t] = lsum;
    __syncthreads();
    for (int off = 128; off > 0; off >>= 1) {
        if (t < off) red[t] += red[t + off];
        __syncthreads();
    }
    float inv = 1.0f / red[0];

    for (int j = t; j <= qpos; j += 256) {
        float p = sc[j] * inv;
        atomicAdd(&vertical[h * S_LEN + j], p);
        atomicAdd(&slash[h * S_LEN + (qpos - j)], p);
    }
}

// ---------------------------------------------------------------------------
// Phase B: exact k-th-largest (radix select) -> membership bitmasks.
// ---------------------------------------------------------------------------
__global__ __launch_bounds__(256) void topk_mask(const float* __restrict__ vertical,
                                                 const float* __restrict__ slash,
                                                 unsigned* __restrict__ col_mask,
                                                 unsigned* __restrict__ diag_mask) {
    int h   = blockIdx.x >> 1;
    int sel = blockIdx.x & 1;
    const float* src = sel ? (slash + h * S_LEN) : (vertical + h * S_LEN);
    unsigned* dst    = sel ? (diag_mask + h * (S_LEN / 32)) : (col_mask + h * (S_LEN / 32));
    int kwant  = sel ? S_TOPK : V_TOPK;
    int forced = sel ? FORCE_S : FORCE_V;
    int t = threadIdx.x;

    __shared__ unsigned keys[S_LEN];
    __shared__ int hist[256];
    __shared__ int sh_digit, sh_want;

    for (int j = t; j < S_LEN; j += 256) {
        float f = (j < forced) ? __builtin_inff() : src[j];
        unsigned u = __float_as_uint(f);
        u = (u & 0x80000000u) ? ~u : (u | 0x80000000u);
        keys[j] = u;
    }
    __syncthreads();

    unsigned prefix = 0;
    int want = kwant;
    for (int shift = 24; shift >= 0; shift -= 8) {
        hist[t] = 0;
        __syncthreads();
        for (int j = t; j < S_LEN; j += 256) {
            unsigned key = keys[j];
            bool match = (shift == 24) || (((key ^ prefix) >> (shift + 8)) == 0);
            if (match) atomicAdd(&hist[(key >> shift) & 255u], 1);
        }
        __syncthreads();
        if (t == 0) {
            int cum = 0, d = 255;
            for (; d >= 0; --d) {
                cum += hist[d];
                if (cum >= want) break;
            }
            sh_digit = d;
            sh_want  = want - (cum - hist[d]);
        }
        __syncthreads();
        prefix |= ((unsigned)sh_digit) << shift;
        want = sh_want;
        __syncthreads();
    }
    for (int w = t; w < S_LEN / 32; w += 256) {
        unsigned bits = 0;
        for (int b = 0; b < 32; ++b)
            if (keys[w * 32 + b] >= prefix) bits |= (1u << b);
        dst[w] = bits;
    }
}

// ---------------------------------------------------------------------------
// Pre-pass: fp32 -> bf16 flat convert (for Q and K).
// ---------------------------------------------------------------------------
__global__ __launch_bounds__(256) void cvt_bf16(const float* __restrict__ src,
                                                unsigned short* __restrict__ dst, int n4) {
    int i = blockIdx.x * 256 + threadIdx.x;
    if (i < n4) {
        float4 v = ((const float4*)src)[i];
        ushort4 o;
        o.x = f2bf(v.x); o.y = f2bf(v.y); o.z = f2bf(v.z); o.w = f2bf(v.w);
        ((ushort4*)dst)[i] = o;
    }
}

// ---------------------------------------------------------------------------
// Pre-pass: V[h][s][d] fp32 -> Vt[h][d][s] bf16 (64x64 LDS tile transpose).
// ---------------------------------------------------------------------------
__global__ __launch_bounds__(256) void transpose_v(const float* __restrict__ v,
                                                   unsigned short* __restrict__ vt) {
    int bx = blockIdx.x;                 // 8 * 2 * 64 = 1024 blocks
    int h  = bx >> 7;
    int rem = bx & 127;
    int d0 = (rem >> 6) * 64;
    int k0 = (rem & 63) * 64;
    __shared__ __align__(16) unsigned short T[64][72];
    int t = threadIdx.x;
#pragma unroll
    for (int it = 0; it < 4; ++it) {
        int idx = t + it * 256;          // 0..1023: r = k row, c4 = d group
        int r = idx >> 4, c4 = idx & 15;
        float4 val = *(const float4*)(v + ((size_t)(h * S_LEN) + k0 + r) * DHEAD + d0 + c4 * 4);
        T[c4 * 4 + 0][r] = f2bf(val.x);
        T[c4 * 4 + 1][r] = f2bf(val.y);
        T[c4 * 4 + 2][r] = f2bf(val.z);
        T[c4 * 4 + 3][r] = f2bf(val.w);
    }
    __syncthreads();
#pragma unroll
    for (int it = 0; it < 2; ++it) {
        int idx = t + it * 256;          // 0..511: r = d row, c8 = k group
        int r = idx >> 3, c8 = idx & 7;
        *(uint4*)(vt + ((size_t)h * DHEAD + d0 + r) * S_LEN + k0 + c8 * 8) = *(uint4*)&T[r][c8 * 8];
    }
}

// ---------------------------------------------------------------------------
// Phase C: MFMA flash attention with vertical-slash mask.
// Block = 256 threads (4 waves) x 64 q-rows; 64-key tiles; D=128.
// ---------------------------------------------------------------------------
#define KS_STRIDE 136   // bf16 elems per K row in LDS (pad: 272B, 16B-mult)
#define VT_STRIDE 72    // bf16 elems per Vt row (144B)
#define PS_STRIDE 72

__global__ __launch_bounds__(256, 3) void sparse_attn_mfma(
        const unsigned short* __restrict__ qbf,
        const unsigned short* __restrict__ kbf,
        const unsigned short* __restrict__ vtbf,
        const unsigned* __restrict__ col_mask,
        const unsigned* __restrict__ diag_mask,
        float* __restrict__ out) {
    int h  = blockIdx.x >> 6;
    int qt = 63 - (blockIdx.x & 63);     // heavy q-tiles first
    int i0 = qt * 64;
    int t    = threadIdx.x;
    int wave = t >> 6;
    int lane = t & 63;
    int ln16 = lane & 15;
    int quad = lane >> 4;

    __shared__ __align__(16) unsigned short Ks[64 * KS_STRIDE];
    __shared__ __align__(16) unsigned short Vt[128 * VT_STRIDE];
    __shared__ __align__(16) unsigned short Ps[4 * 16 * PS_STRIDE];
    __shared__ u64 allowed[64];
    __shared__ unsigned dmLDS[130];

    if (t < 130) dmLDS[t] = (t < 128) ? diag_mask[h * 128 + t] : 0u;

    // Q fragments (A-layout), resident in registers for all tiles
    int qrow = i0 + wave * 16 + ln16;
    const unsigned short* qp = qbf + ((size_t)h * S_LEN + qrow) * DHEAD;
    short8 qf[4];
#pragma unroll
    for (int ds = 0; ds < 4; ++ds)
        qf[ds] = *(const short8*)(qp + ds * 32 + quad * 8);

    floatx4 o4[8];
#pragma unroll
    for (int n = 0; n < 8; ++n) o4[n] = (floatx4){0.f, 0.f, 0.f, 0.f};
    float m_run[4] = {-3.0e38f, -3.0e38f, -3.0e38f, -3.0e38f};
    float l_run[4] = {0.f, 0.f, 0.f, 0.f};

    unsigned short* psw = Ps + wave * 16 * PS_STRIDE;

    for (int jt = 0; jt <= qt; ++jt) {
        int j0 = jt * 64;
        __syncthreads();   // previous tile's reads done (also covers dmLDS on iter 0)

        // ---- stage K tile [64][128] bf16 ----
#pragma unroll
        for (int it = 0; it < 4; ++it) {
            int idx = t + it * 256;
            int r = idx >> 4, c8 = idx & 15;
            *(uint4*)&Ks[r * KS_STRIDE + c8 * 8] =
                *(const uint4*)(kbf + ((size_t)(h * S_LEN) + j0 + r) * DHEAD + c8 * 8);
        }
        // ---- stage Vt tile [128][64] bf16 ----
#pragma unroll
        for (int it = 0; it < 4; ++it) {
            int idx = t + it * 256;
            int r = idx >> 3, c8 = idx & 7;
            *(uint4*)&Vt[r * VT_STRIDE + c8 * 8] =
                *(const uint4*)(vtbf + ((size_t)h * DHEAD + r) * S_LEN + j0 + c8 * 8);
        }
        // ---- build per-row allowed bitmask ----
        if (t < 64) {
            int i = i0 + t;
            int off0 = i - j0;                       // >= 0
            u64 causal = (off0 >= 63) ? ~0ull : ((1ull << (off0 + 1)) - 1ull);
            u64 cwv = ((u64)col_mask[h * 128 + (j0 >> 5) + 1] << 32) |
                      (u64)col_mask[h * 128 + (j0 >> 5)];
            int sb = off0 - 63;
            u64 V;
            if (sb >= 0) {
                int w = sb >> 5, sh = sb & 31;
                u64 lo = ((u64)dmLDS[w + 1] << 32) | (u64)dmLDS[w];
                u64 hi = (u64)dmLDS[w + 2];
                V = (lo >> sh) | (sh ? (hi << (64 - sh)) : 0ull);
            } else {
                u64 w0 = ((u64)dmLDS[1] << 32) | (u64)dmLDS[0];
                V = w0 << (-sb);
            }
            allowed[t] = (cwv | __brevll(V)) & causal;
        }
        __syncthreads();

        // ---- S = Q K^T : 4 column tiles of 16 ----
        floatx4 s_acc[4];
#pragma unroll
        for (int c = 0; c < 4; ++c) {
            s_acc[c] = (floatx4){0.f, 0.f, 0.f, 0.f};
            const unsigned short* kbase = Ks + (c * 16 + ln16) * KS_STRIDE + quad * 8;
#pragma unroll
            for (int ds = 0; ds < 4; ++ds) {
                short8 kf = *(const short8*)(kbase + ds * 32);
                s_acc[c] = __builtin_amdgcn_mfma_f32_16x16x32_bf16(qf[ds], kf, s_acc[c], 0, 0, 0);
            }
        }

        // ---- mask + scale ----
        u64 Arow[4];
#pragma unroll
        for (int r = 0; r < 4; ++r)
            Arow[r] = allowed[wave * 16 + quad * 4 + r];
        float sc[4][4];
#pragma unroll
        for (int c = 0; c < 4; ++c)
#pragma unroll
            for (int r = 0; r < 4; ++r) {
                bool ok = (Arow[r] >> (c * 16 + ln16)) & 1ull;
                sc[c][r] = ok ? s_acc[c][r] * SCALE : -__builtin_inff();
            }

        // ---- online softmax (rows live across 16-lane groups) ----
        float mnew[4], alpha[4];
#pragma unroll
        for (int r = 0; r < 4; ++r) {
            float mx = fmaxf(fmaxf(sc[0][r], sc[1][r]), fmaxf(sc[2][r], sc[3][r]));
#pragma unroll
            for (int d = 8; d >= 1; d >>= 1) mx = fmaxf(mx, __shfl_xor(mx, d, 64));
            mnew[r] = fmaxf(m_run[r], mx);
            alpha[r] = __expf(m_run[r] - mnew[r]);
            m_run[r] = mnew[r];
        }
        float pv[4][4];
#pragma unroll
        for (int r = 0; r < 4; ++r) {
            float su = 0.f;
#pragma unroll
            for (int c = 0; c < 4; ++c) {
                float p = __expf(sc[c][r] - mnew[r]);
                pv[c][r] = p;
                su += p;
            }
#pragma unroll
            for (int d = 8; d >= 1; d >>= 1) su += __shfl_xor(su, d, 64);
            l_run[r] = l_run[r] * alpha[r] + su;
        }
#pragma unroll
        for (int n = 0; n < 8; ++n)
#pragma unroll
            for (int r = 0; r < 4; ++r) o4[n][r] *= alpha[r];

        // ---- P (C-layout) -> wave-private LDS -> A-layout fragments ----
#pragma unroll
        for (int c = 0; c < 4; ++c)
#pragma unroll
            for (int r = 0; r < 4; ++r)
                psw[(quad * 4 + r) * PS_STRIDE + c * 16 + ln16] = f2bf(pv[c][r]);
        asm volatile("" ::: "memory");   // keep compiler from hoisting the reads
        short8 pf0 = *(const short8*)&psw[ln16 * PS_STRIDE + quad * 8];
        short8 pf1 = *(const short8*)&psw[ln16 * PS_STRIDE + 32 + quad * 8];

        // ---- O += P V ----
#pragma unroll
        for (int n = 0; n < 8; ++n) {
            const unsigned short* vbase = Vt + (n * 16 + ln16) * VT_STRIDE + quad * 8;
            short8 vf0 = *(const short8*)(vbase);
            short8 vf1 = *(const short8*)(vbase + 32);
            o4[n] = __builtin_amdgcn_mfma_f32_16x16x32_bf16(pf0, vf0, o4[n], 0, 0, 0);
            o4[n] = __builtin_amdgcn_mfma_f32_16x16x32_bf16(pf1, vf1, o4[n], 0, 0, 0);
        }
    }

    // ---- epilogue ----
#pragma unroll
    for (int r = 0; r < 4; ++r) {
        float invl = 1.0f / l_run[r];
        int row = i0 + wave * 16 + quad * 4 + r;
        float* op = out + ((size_t)h * S_LEN + row) * DHEAD;
#pragma unroll
        for (int n = 0; n < 8; ++n)
            op[n * 16 + ln16] = o4[n][r] * invl;
    }
}

// ---------------------------------------------------------------------------
extern "C" void kernel_launch(void* const* d_in, const int* in_sizes, int n_in,
                              void* d_out, int out_size, void* d_ws, size_t ws_size,
                              hipStream_t stream) {
    const float* q = (const float*)d_in[0];
    const float* k = (const float*)d_in[1];
    const float* v = (const float*)d_in[2];
    float* out = (float*)d_out;

    float* vertical = (float*)d_ws;                            // 8*4096 f32
    float* slash    = vertical + NHEAD * S_LEN;                // 8*4096 f32
    unsigned* col_m  = (unsigned*)(slash + NHEAD * S_LEN);     // 8*128 u32
    unsigned* diag_m = col_m + NHEAD * (S_LEN / 32);           // 8*128 u32
    unsigned short* qbf  = (unsigned short*)(diag_m + NHEAD * (S_LEN / 32));
    unsigned short* kbf  = qbf + (size_t)NHEAD * S_LEN * DHEAD;
    unsigned short* vtbf = kbf + (size_t)NHEAD * S_LEN * DHEAD;

    hipMemsetAsync(d_ws, 0, (size_t)2 * NHEAD * S_LEN * sizeof(float), stream);

    int n4 = NHEAD * S_LEN * DHEAD / 4;
    cvt_bf16<<<(n4 + 255) / 256, 256, 0, stream>>>(q, qbf, n4);
    cvt_bf16<<<(n4 + 255) / 256, 256, 0, stream>>>(k, kbf, n4);
    transpose_v<<<NHEAD * 2 * (S_LEN / 64), 256, 0, stream>>>(v, vtbf);

    pattern_rows<<<NHEAD * LASTQ, 256, 0, stream>>>(q, k, vertical, slash);
    topk_mask<<<NHEAD * 2, 256, 0, stream>>>(vertical, slash, col_m, diag_m);

    sparse_attn_mfma<<<NHEAD * 64, 256, 0, stream>>>(qbf, kbf, vtbf, col_m, diag_m, out);
}